// Round 3
// baseline (677.518 us; speedup 1.0000x reference)
//
#include <hip/hip_runtime.h>

// Prompts: out[row,k] = softmax_k( 100 * dot(x[row,:], tf[k,:]/||tf[k]||) )
// rows = 262144, D = 512, K = 2.
// Traffic floor: read 512 MiB x + write 2 MiB out ~= 85 us @ 6.3 TB/s.
// Harness fixed cost (r1/r2 counters): 2 GiB ws poison ~335 us @6.4 TB/s +
// ~165 us input restore => ~500 us of the ~650 us headline.
// r1->r2 post-mortem: reduction restructure NEUTRAL => kernel (~150 us,
// ~3.6 TB/s) is not issue/dependency-bound. This round: occupancy. Grid was
// 1024 blocks = 4 blocks/CU = 16/32 waves/CU. Shrink to <=64 VGPR/thread
// (32-lane group per row: 12 vfloat4 of live data), launch_bounds(256,8),
// 2048 blocks => 32 waves/CU. Also drop nt from loads (6.29 TB/s m13 copy
// used plain loads); keep nt on the 2 MiB output store.
// Predict: kernel ~150 -> ~100 us, headline ~600 us.

#define D_DIM 512

typedef float vfloat4 __attribute__((ext_vector_type(4)));
typedef float vfloat2 __attribute__((ext_vector_type(2)));

__device__ __forceinline__ float dot4(vfloat4 a, vfloat4 b) {
    return a.x * b.x + a.y * b.y + a.z * b.z + a.w * b.w;
}

__global__ __launch_bounds__(256, 8) void prompts_kernel(
    const float* __restrict__ x,
    const float* __restrict__ tf,
    const float* __restrict__ logit_scale,
    float* __restrict__ out,
    int nrows)
{
    const int lane          = threadIdx.x & 63;
    const int t             = lane & 31;   // sublane within 32-lane group
    const int g             = lane >> 5;   // group 0..1; group owns one row
    const int wave_in_block = threadIdx.x >> 6;
    const int gwave  = blockIdx.x * (blockDim.x >> 6) + wave_in_block;
    const int nwaves = gridDim.x * (blockDim.x >> 6);

    // ---- Weights: sublane t keeps slices t+32j (j=0..3) of both tf rows.
    //      48 data VGPRs total (w0[4], w1[4], xv[4]) -- fits 64-VGPR budget
    //      so 8 waves/SIMD can be resident.
    const vfloat4* tf4 = (const vfloat4*)tf;
    vfloat4 w0[4], w1[4];
#pragma unroll
    for (int j = 0; j < 4; ++j) {
        w0[j] = tf4[t + 32 * j];
        w1[j] = tf4[128 + t + 32 * j];
    }

    float ss0 = 0.f, ss1 = 0.f;
#pragma unroll
    for (int j = 0; j < 4; ++j) {
        ss0 += dot4(w0[j], w0[j]);
        ss1 += dot4(w1[j], w1[j]);
    }
#pragma unroll
    for (int off = 16; off >= 1; off >>= 1) {   // reduce across 32 sublanes
        ss0 += __shfl_xor(ss0, off, 64);
        ss1 += __shfl_xor(ss1, off, 64);
    }

    const float scale = expf(logit_scale[0]);   // = 100.0
    const float inv0  = scale / sqrtf(ss0);
    const float inv1  = scale / sqrtf(ss1);
#pragma unroll
    for (int j = 0; j < 4; ++j) { w0[j] *= inv0; w1[j] *= inv1; }

    // ---- Persistent grid-stride: 2 rows (4 KiB) per wave-iteration,
    //      one row per 32-lane group. Pointer strength-reduced.
    const vfloat4* x4   = (const vfloat4*)x;
    vfloat2*       out2 = (vfloat2*)out;

    const size_t   step = (size_t)nwaves * 2 * (D_DIM / 4);
    const vfloat4* p    = x4 + (size_t)(gwave * 2 + g) * (D_DIM / 4) + t;

    for (int row0 = gwave * 2; row0 < nrows; row0 += nwaves * 2, p += step) {
        // 4 plain 16B loads; per instruction the wave touches 2 contiguous
        // 512B segments (one per group) -- fully coalesced cachelines.
        vfloat4 xv[4];
#pragma unroll
        for (int j = 0; j < 4; ++j) xv[j] = p[32 * j];

        float a = 0.f, b = 0.f;
#pragma unroll
        for (int j = 0; j < 4; ++j) {
            a += dot4(xv[j], w0[j]);
            b += dot4(xv[j], w1[j]);
        }

        // 5-stage butterfly within the 32-lane group.
#pragma unroll
        for (int off = 16; off >= 1; off >>= 1) {
            a += __shfl_xor(a, off, 64);
            b += __shfl_xor(b, off, 64);
        }

        if (t == 0) {
            // softmax over 2: overflow-safe (exp->inf => p->0)
            vfloat2 pr;
            pr.x = 1.0f / (1.0f + expf(b - a));
            pr.y = 1.0f / (1.0f + expf(a - b));
            __builtin_nontemporal_store(pr, out2 + row0 + g);
        }
    }
}

extern "C" void kernel_launch(void* const* d_in, const int* in_sizes, int n_in,
                              void* d_out, int out_size, void* d_ws, size_t ws_size,
                              hipStream_t stream) {
    const float* x  = (const float*)d_in[0];
    const float* tf = (const float*)d_in[1];
    const float* ls = (const float*)d_in[2];
    float* out = (float*)d_out;

    const int nrows = in_sizes[0] / D_DIM;  // 262144

    // 2048 blocks x 256 thr = 8192 waves; 8 blocks/CU co-resident at <=64
    // VGPR => 32 waves/CU (was 16). 16 iterations per wave, 2 rows/iter.
    prompts_kernel<<<2048, 256, 0, stream>>>(x, tf, ls, out, nrows);
}

// Round 4
// 659.597 us; speedup vs baseline: 1.0272x; 1.0272x over previous
//
#include <hip/hip_runtime.h>

// Prompts: out[row,k] = softmax_k( 100 * dot(x[row,:], tf[k,:]/||tf[k]||) )
// rows = 262144, D = 512, K = 2.
// Traffic floor: read 512 MiB x + write 2 MiB out ~= 85 us @ 6.3 TB/s.
// Cost model (r1-r3 consistent): fill ~334 + restore ~168 + kernel = headline.
//   r1 kernel ~149 (nt, 16 waves/CU), r2 ~146 (nt, 16 w/CU), r3 ~175 (plain,
//   32 w/CU). r3 confounded two variables.
// THIS ROUND: single-variable isolation -- r3 body EXACTLY, with nontemporal
// restored on the 4 x-loads. A/B vs r3 isolates nt; A/B vs r2 isolates
// occupancy (body structure proven neutral by r1~r2).
// Predict: H1 (nt was the regression): headline ~647; H1+occupancy-helps:
// ~615; H2 (occupancy was the regression): ~675 -> revert next round.

#define D_DIM 512

typedef float vfloat4 __attribute__((ext_vector_type(4)));
typedef float vfloat2 __attribute__((ext_vector_type(2)));

__device__ __forceinline__ float dot4(vfloat4 a, vfloat4 b) {
    return a.x * b.x + a.y * b.y + a.z * b.z + a.w * b.w;
}

__device__ __forceinline__ vfloat4 nt_load4(const vfloat4* p) {
    return __builtin_nontemporal_load(p);
}

__global__ __launch_bounds__(256, 8) void prompts_kernel(
    const float* __restrict__ x,
    const float* __restrict__ tf,
    const float* __restrict__ logit_scale,
    float* __restrict__ out,
    int nrows)
{
    const int lane          = threadIdx.x & 63;
    const int t             = lane & 31;   // sublane within 32-lane group
    const int g             = lane >> 5;   // group 0..1; group owns one row
    const int wave_in_block = threadIdx.x >> 6;
    const int gwave  = blockIdx.x * (blockDim.x >> 6) + wave_in_block;
    const int nwaves = gridDim.x * (blockDim.x >> 6);

    // ---- Weights: sublane t keeps slices t+32j (j=0..3) of both tf rows.
    //      48 data VGPRs (w0[4], w1[4], xv[4]) -- fits the 64-VGPR budget
    //      so 8 waves/SIMD can be resident.
    const vfloat4* tf4 = (const vfloat4*)tf;
    vfloat4 w0[4], w1[4];
#pragma unroll
    for (int j = 0; j < 4; ++j) {
        w0[j] = tf4[t + 32 * j];
        w1[j] = tf4[128 + t + 32 * j];
    }

    float ss0 = 0.f, ss1 = 0.f;
#pragma unroll
    for (int j = 0; j < 4; ++j) {
        ss0 += dot4(w0[j], w0[j]);
        ss1 += dot4(w1[j], w1[j]);
    }
#pragma unroll
    for (int off = 16; off >= 1; off >>= 1) {   // reduce across 32 sublanes
        ss0 += __shfl_xor(ss0, off, 64);
        ss1 += __shfl_xor(ss1, off, 64);
    }

    const float scale = expf(logit_scale[0]);   // = 100.0
    const float inv0  = scale / sqrtf(ss0);
    const float inv1  = scale / sqrtf(ss1);
#pragma unroll
    for (int j = 0; j < 4; ++j) { w0[j] *= inv0; w1[j] *= inv1; }

    // ---- Persistent grid-stride: 2 rows (4 KiB) per wave-iteration,
    //      one row per 32-lane group. Pointer strength-reduced.
    const vfloat4* x4   = (const vfloat4*)x;
    vfloat2*       out2 = (vfloat2*)out;

    const size_t   step = (size_t)nwaves * 2 * (D_DIM / 4);
    const vfloat4* p    = x4 + (size_t)(gwave * 2 + g) * (D_DIM / 4) + t;

    for (int row0 = gwave * 2; row0 < nrows; row0 += nwaves * 2, p += step) {
        // 4 nontemporal 16B loads; per instruction the wave touches 2
        // contiguous 512B segments (one per group) -- fully coalesced.
        vfloat4 xv[4];
#pragma unroll
        for (int j = 0; j < 4; ++j) xv[j] = nt_load4(p + 32 * j);

        float a = 0.f, b = 0.f;
#pragma unroll
        for (int j = 0; j < 4; ++j) {
            a += dot4(xv[j], w0[j]);
            b += dot4(xv[j], w1[j]);
        }

        // 5-stage butterfly within the 32-lane group.
#pragma unroll
        for (int off = 16; off >= 1; off >>= 1) {
            a += __shfl_xor(a, off, 64);
            b += __shfl_xor(b, off, 64);
        }

        if (t == 0) {
            // softmax over 2: overflow-safe (exp->inf => p->0)
            vfloat2 pr;
            pr.x = 1.0f / (1.0f + expf(b - a));
            pr.y = 1.0f / (1.0f + expf(a - b));
            __builtin_nontemporal_store(pr, out2 + row0 + g);
        }
    }
}

extern "C" void kernel_launch(void* const* d_in, const int* in_sizes, int n_in,
                              void* d_out, int out_size, void* d_ws, size_t ws_size,
                              hipStream_t stream) {
    const float* x  = (const float*)d_in[0];
    const float* tf = (const float*)d_in[1];
    const float* ls = (const float*)d_in[2];
    float* out = (float*)d_out;

    const int nrows = in_sizes[0] / D_DIM;  // 262144

    // 2048 blocks x 256 thr = 8192 waves; 8 blocks/CU co-resident at <=64
    // VGPR => 32 waves/CU. 16 iterations per wave, 2 rows/iter.
    prompts_kernel<<<2048, 256, 0, stream>>>(x, tf, ls, out, nrows);
}